// Round 2
// baseline (948.948 us; speedup 1.0000x reference)
//
#include <hip/hip_runtime.h>
#include <cstdint>
#include <cstddef>

typedef unsigned int  uint_t;
typedef unsigned short ushort_t;

// ---- shapes (fixed for this problem) ----
constexpr int B_  = 64;
constexpr int S_  = 128;
constexpr int D_  = 100;   // triple embedding dim
constexpr int E_  = 300;   // word embedding dim
constexpr int H_  = 256;   // hidden
constexpr int KIN = 512;   // LSTM input 500 padded to 512 for MFMA K
constexpr int NG  = 1024;  // 4*H gates
constexpr int M_  = B_ * S_;  // 8192

// ---- workspace layout (bytes) ----
constexpr size_t OFF_WT   = 0;                                  // W_ent^T bf16 [200][100]  (40000 B)
constexpr size_t OFF_FLAG = 40000;                              // int: 1 if inputs are fp32, 0 if bf16
constexpr size_t OFF_WIH  = 40960;                              // W_ih padded bf16 [1024][512]
constexpr size_t OFF_WHH  = OFF_WIH + (size_t)NG * KIN * 2;     // W_hh as f16x2, [128][1024] u32
constexpr size_t OFF_TIN  = OFF_WHH + (size_t)128 * NG * 4;     // t_in bf16 [8192][512]
constexpr size_t OFF_XG   = OFF_TIN + (size_t)M_ * KIN * 2;     // xg f32 [8192][1024]
constexpr size_t OFF_HOUT = OFF_XG + (size_t)M_ * NG * 4;       // h f32 [8192][256]
// total ~50 MB

// ---- helpers ----
__device__ __forceinline__ float b2f(ushort_t u) {
  union { uint_t u; float f; } v; v.u = ((uint_t)u) << 16; return v.f;
}
__device__ __forceinline__ float blo(uint_t u) {
  union { uint_t u; float f; } v; v.u = u << 16; return v.f;
}
__device__ __forceinline__ float bhi(uint_t u) {
  union { uint_t u; float f; } v; v.u = u & 0xffff0000u; return v.f;
}
__device__ __forceinline__ ushort_t f2b(float f) {  // RNE float->bf16
  union { float f; uint_t u; } v; v.f = f;
  uint_t r = (v.u + 0x7fffu + ((v.u >> 16) & 1u)) >> 16;
  return (ushort_t)r;
}
__device__ __forceinline__ ushort_t f16bits(float f) {
  _Float16 h = (_Float16)f;
  union { _Float16 h; ushort_t u; } v; v.h = h; return v.u;
}
__device__ __forceinline__ float fast_tanh(float x) {
  float e = __expf(2.f * x);
  return 1.f - 2.f / (e + 1.f);
}
__device__ __forceinline__ float sigm(float x) {
  return 1.f / (1.f + __expf(-x));
}
// dtype-flexible load of an external "float" tensor
__device__ __forceinline__ float ldv(const void* p, size_t i, int f32) {
  return f32 ? ((const float*)p)[i] : b2f(((const ushort_t*)p)[i]);
}

#if defined(__has_builtin)
#if __has_builtin(__builtin_amdgcn_fdot2)
#define HAVE_FDOT2 1
#endif
#endif

typedef _Float16 half2v __attribute__((ext_vector_type(2)));

__device__ __forceinline__ float dot2(uint_t w, uint_t h, float acc) {
#ifdef HAVE_FDOT2
  union { uint_t u; half2v v; } a, b; a.u = w; b.u = h;
  return __builtin_amdgcn_fdot2(a.v, b.v, acc, false);
#else
  union { uint_t u; _Float16 h[2]; } a, b; a.u = w; b.u = h;
  acc += (float)a.h[0] * (float)b.h[0];
  acc += (float)a.h[1] * (float)b.h[1];
  return acc;
#endif
}

// =====================================================================
// K_detect: decide whether external float tensors are fp32 or bf16.
// View embedding as u32 words. Low ushort as bf16: exponent>=140 means
// |v|>=2^13 — p~0.45/word if fp32 storage (mantissa bits), p~0 if bf16
// (values ~N(0,0.02)). 512 samples, threshold 32.
// =====================================================================
__global__ __launch_bounds__(64) void k_detect(const uint_t* __restrict__ emb_w,
                                               char* __restrict__ ws)
{
  int tid = threadIdx.x;
  int hits = 0;
  for (int i = 0; i < 8; ++i) {
    uint_t w = emb_w[i * 64 + tid];
    uint_t e = (w >> 7) & 0xffu;   // exponent field of lo-ushort-as-bf16
    hits += (e >= 140) ? 1 : 0;
  }
  for (int off = 32; off > 0; off >>= 1) hits += __shfl_down(hits, off);
  if (tid == 0) *(int*)(ws + OFF_FLAG) = (hits >= 32) ? 1 : 0;
}

// =====================================================================
// K0: weight prep. Wt = W_ent^T (bf16); W_ih padded K 500->512 (bf16);
// W_hh -> f16x2 packed, transposed to [kpair][row] for coalesced loads.
// =====================================================================
__global__ __launch_bounds__(256) void k0_prep(
    const void* __restrict__ W_ent, const void* __restrict__ W_ih,
    const void* __restrict__ W_hh, char* __restrict__ ws)
{
  const int f32 = *(const int*)(ws + OFF_FLAG);
  int id = blockIdx.x * 256 + threadIdx.x;
  ushort_t* Wt = (ushort_t*)(ws + OFF_WT);
  ushort_t* Wp = (ushort_t*)(ws + OFF_WIH);
  uint_t*   WT = (uint_t*)(ws + OFF_WHH);
  if (id < 20000) {
    int k = id / 100, d = id % 100;
    Wt[id] = f2b(ldv(W_ent, (size_t)d * 200 + k, f32));   // Wt[k][d] = W_ent[d][k]
  } else if (id < 20000 + NG * KIN) {
    int i = id - 20000;
    int n = i >> 9, k = i & 511;
    Wp[i] = (k < 500) ? f2b(ldv(W_ih, (size_t)n * 500 + k, f32)) : (ushort_t)0;
  } else if (id < 20000 + NG * KIN + 128 * NG) {
    int i = id - 20000 - NG * KIN;
    int kk = i >> 10, j = i & 1023;
    ushort_t lo = f16bits(ldv(W_hh, (size_t)j * 256 + 2 * kk,     f32));
    ushort_t hi = f16bits(ldv(W_hh, (size_t)j * 256 + 2 * kk + 1, f32));
    WT[kk * 1024 + j] = (uint_t)lo | ((uint_t)hi << 16);
  }
}

// =====================================================================
// K1: triple graph attention per (b,s); writes t_in bf16 [m][512]:
// cols 0..299 = embedding row, 300..499 = graph, 500..511 = 0
// =====================================================================
__global__ __launch_bounds__(128) void k1_graph(
    const int* __restrict__ inputs, const int* __restrict__ triples,
    const int* __restrict__ id2, const void* __restrict__ emb,
    const void* __restrict__ ent, const void* __restrict__ rel,
    char* __restrict__ ws)
{
  __shared__ __align__(16) ushort_t Wl[20000];   // W^T [k][d], 40000 B
  __shared__ float ht_l[10][200];
  __shared__ float er_l[10][100];
  __shared__ float e_l[10];
  __shared__ float alpha_l[10];
  __shared__ int   trip_l[30];
  __shared__ int   vflag;

  const int tid = threadIdx.x;
  const int m   = blockIdx.x;  // b*128+s
  const int f32 = *(const int*)(ws + OFF_FLAG);
  const ushort_t* Wt = (const ushort_t*)(ws + OFF_WT);
  ushort_t* tin = (ushort_t*)(ws + OFF_TIN);

  if (tid < 30) trip_l[tid] = triples[(size_t)m * 30 + tid];
  if (tid == 0) vflag = 0;
  if (tid < 10) e_l[tid] = 0.f;
  __syncthreads();
  if (tid < 10 && id2[(size_t)m * 10 + tid] != -1) atomicOr(&vflag, 1);

  // stage W^T (coalesced 16B copies)
  {
    const uint4* src = (const uint4*)Wt;
    uint4* dst = (uint4*)Wl;
    for (int i = tid; i < 2500; i += 128) dst[i] = src[i];
  }
  // stage ht = [e_head, e_tail] per triple (fp32)
  for (int i = tid; i < 2000; i += 128) {
    int t = i / 200, k = i % 200;
    int row = trip_l[t * 3 + (k < 100 ? 0 : 1)];
    int kk = (k < 100) ? k : k - 100;
    ht_l[t][k] = ldv(ent, (size_t)row * 100 + kk, f32);
  }
  // stage er
  for (int i = tid; i < 1000; i += 128) {
    int t = i / 100, d = i % 100;
    er_l[t][d] = ldv(rel, (size_t)trip_l[t * 3 + 2] * 100 + d, f32);
  }
  // x part of t_in (bf16; exact copy when storage is bf16) + zero pad
  {
    int w = inputs[m];
    for (int c = tid; c < 300; c += 128)
      tin[(size_t)m * KIN + c] = f2b(ldv(emb, (size_t)w * E_ + c, f32));
    if (tid < 12) tin[(size_t)m * KIN + 500 + tid] = 0;
  }
  __syncthreads();

  // 1000 dots (t,d) of length 200; thread tile = 2 t's x 4 d's
  if (tid < 125) {
    int t2 = tid / 25, d4 = tid % 25;
    int t0 = 2 * t2, t1 = t0 + 1;
    float a00 = 0, a01 = 0, a02 = 0, a03 = 0;
    float a10 = 0, a11 = 0, a12 = 0, a13 = 0;
    for (int k = 0; k < 200; ++k) {
      uint2 wu = *(const uint2*)&Wl[k * 100 + 4 * d4];
      float h0 = ht_l[t0][k], h1 = ht_l[t1][k];
      float w0 = blo(wu.x), w1 = bhi(wu.x), w2 = blo(wu.y), w3 = bhi(wu.y);
      a00 += w0 * h0; a01 += w1 * h0; a02 += w2 * h0; a03 += w3 * h0;
      a10 += w0 * h1; a11 += w1 * h1; a12 += w2 * h1; a13 += w3 * h1;
    }
    int d = 4 * d4;
    float s0 = fast_tanh(a00) * er_l[t0][d]     + fast_tanh(a01) * er_l[t0][d + 1]
             + fast_tanh(a02) * er_l[t0][d + 2] + fast_tanh(a03) * er_l[t0][d + 3];
    float s1 = fast_tanh(a10) * er_l[t1][d]     + fast_tanh(a11) * er_l[t1][d + 1]
             + fast_tanh(a12) * er_l[t1][d + 2] + fast_tanh(a13) * er_l[t1][d + 3];
    atomicAdd(&e_l[t0], s0);
    atomicAdd(&e_l[t1], s1);
  }
  __syncthreads();
  if (tid == 0) {  // softmax over 10 triples
    float mx = e_l[0];
    for (int t = 1; t < 10; ++t) mx = fmaxf(mx, e_l[t]);
    float s = 0.f;
    for (int t = 0; t < 10; ++t) { float v = __expf(e_l[t] - mx); alpha_l[t] = v; s += v; }
    float inv = 1.f / s;
    for (int t = 0; t < 10; ++t) alpha_l[t] *= inv;
  }
  __syncthreads();
  for (int k2 = tid; k2 < 200; k2 += 128) {
    float g = 0.f;
#pragma unroll
    for (int t = 0; t < 10; ++t) g += alpha_l[t] * ht_l[t][k2];
    if (!vflag) g = 0.f;
    tin[(size_t)m * KIN + 300 + k2] = f2b(g);
  }
}

// =====================================================================
// K2: xg = t_in @ W_ih^T + b.  MFMA 16x16x32 bf16, 128x128 tiles, BK=32.
// =====================================================================
typedef __attribute__((ext_vector_type(8))) short short8;
typedef __attribute__((ext_vector_type(4))) float f32x4;

__global__ __launch_bounds__(256) void k2_xg(
    const void* __restrict__ bl, char* __restrict__ ws)
{
  __shared__ __align__(16) ushort_t As[128 * 32];
  __shared__ __align__(16) ushort_t Bs[128 * 32];
  const ushort_t* A  = (const ushort_t*)(ws + OFF_TIN);
  const ushort_t* Bw = (const ushort_t*)(ws + OFF_WIH);
  float* xg = (float*)(ws + OFF_XG);
  const int f32 = *(const int*)(ws + OFF_FLAG);

  const int tid = threadIdx.x;
  const int m0 = blockIdx.x * 128;
  const int n0 = blockIdx.y * 128;
  const int lane = tid & 63, wv = tid >> 6;
  const int wm = wv & 1, wn = wv >> 1;      // 2x2 wave grid, 64x64 per wave
  const int g = lane >> 4, r = lane & 15;

  f32x4 acc[4][4] = {};

  for (int ks = 0; ks < 16; ++ks) {
    const int k0 = ks * 32;
    {
      int c0 = tid, c1 = tid + 256;   // 512 chunks of 16B per matrix
      uint4 a0 = *(const uint4*)(A  + (size_t)(m0 + (c0 >> 2)) * KIN + k0 + ((c0 & 3) << 3));
      uint4 a1 = *(const uint4*)(A  + (size_t)(m0 + (c1 >> 2)) * KIN + k0 + ((c1 & 3) << 3));
      uint4 b0 = *(const uint4*)(Bw + (size_t)(n0 + (c0 >> 2)) * KIN + k0 + ((c0 & 3) << 3));
      uint4 b1 = *(const uint4*)(Bw + (size_t)(n0 + (c1 >> 2)) * KIN + k0 + ((c1 & 3) << 3));
      ((uint4*)As)[c0] = a0; ((uint4*)As)[c1] = a1;
      ((uint4*)Bs)[c0] = b0; ((uint4*)Bs)[c1] = b1;
    }
    __syncthreads();
    short8 av[4], bv[4];
#pragma unroll
    for (int i = 0; i < 4; ++i)
      av[i] = *(const short8*)&As[(wm * 64 + i * 16 + r) * 32 + g * 8];
#pragma unroll
    for (int j = 0; j < 4; ++j)
      bv[j] = *(const short8*)&Bs[(wn * 64 + j * 16 + r) * 32 + g * 8];
#pragma unroll
    for (int i = 0; i < 4; ++i)
#pragma unroll
      for (int j = 0; j < 4; ++j)
        acc[i][j] = __builtin_amdgcn_mfma_f32_16x16x32_bf16(av[i], bv[j], acc[i][j], 0, 0, 0);
    __syncthreads();
  }
  // epilogue: C/D layout col=lane&15, row=(lane>>4)*4+reg
#pragma unroll
  for (int j = 0; j < 4; ++j) {
    int n = n0 + wn * 64 + j * 16 + r;
    float bias = ldv(bl, n, f32);
#pragma unroll
    for (int i = 0; i < 4; ++i) {
      int mrow = m0 + wm * 64 + i * 16 + g * 4;
#pragma unroll
      for (int rr = 0; rr < 4; ++rr)
        xg[(size_t)(mrow + rr) * NG + n] = acc[i][j][rr] + bias;
    }
  }
}

// =====================================================================
// K3: recurrent LSTM. One block per batch; thread owns 2 gate rows;
// W_hh f16-packed in 256 VGPRs; h broadcast from LDS as f16x2.
// =====================================================================
__global__ __launch_bounds__(512, 1) void k3_lstm(char* __restrict__ ws)
{
  __shared__ uint_t hl[128];            // h as f16x2 (256 dims)
  __shared__ float sf_l[256], so_l[256];

  const int tid = threadIdx.x;
  const int b = blockIdx.x;
  const int half = tid >> 8, idx = tid & 255;
  const int row0 = (half == 0) ? idx : idx + 256;        // i | f
  const int row1 = (half == 0) ? idx + 512 : idx + 768;  // g | o

  const uint_t* WT = (const uint_t*)(ws + OFF_WHH);  // [kpair][1024]
  const float* xg = (const float*)(ws + OFF_XG);
  float* hout = (float*)(ws + OFF_HOUT);

  uint_t w0[128], w1[128];
#pragma unroll
  for (int kk = 0; kk < 128; ++kk) {
    w0[kk] = WT[kk * 1024 + row0];
    w1[kk] = WT[kk * 1024 + row1];
  }
  if (tid < 128) hl[tid] = 0u;
  float c = 0.f;
  __syncthreads();

  const int bm = b * S_;
  for (int t = 0; t < S_; ++t) {
    const float* xp = xg + (size_t)(bm + t) * NG;
    float a0 = xp[row0];
    float a1 = xp[row1];
#pragma unroll
    for (int kk = 0; kk < 64; ++kk) {
      uint2 hv = *(const uint2*)&hl[2 * kk];
      a0 = dot2(w0[2 * kk],     hv.x, a0);
      a0 = dot2(w0[2 * kk + 1], hv.y, a0);
      a1 = dot2(w1[2 * kk],     hv.x, a1);
      a1 = dot2(w1[2 * kk + 1], hv.y, a1);
    }
    if (half == 1) {
      sf_l[idx] = sigm(a0);    // sigmoid(f)
      so_l[idx] = sigm(a1);    // sigmoid(o)
    }
    __syncthreads();           // dots done reading hl; sf/so visible
    if (half == 0) {
      float ci = sigm(a0), cg = fast_tanh(a1);
      c = sf_l[idx] * c + ci * cg;
      float hv = so_l[idx] * fast_tanh(c);
      hout[(size_t)(bm + t) * H_ + idx] = hv;
      ((ushort_t*)hl)[idx] = f16bits(hv);
    }
    __syncthreads();           // new h visible
  }
}

// =====================================================================
// K4: masked attention pooling + logits. One block per batch.
// =====================================================================
__global__ __launch_bounds__(256) void k4_attn(
    const int* __restrict__ lengths, const void* __restrict__ attn_w,
    const void* __restrict__ attn_b, const void* __restrict__ out_w,
    const void* __restrict__ out_b, const char* __restrict__ ws,
    void* __restrict__ out)
{
  __shared__ float aw[256];
  __shared__ float sc[128];
  __shared__ float at[256];
  __shared__ float red[256];

  const int tid = threadIdx.x;
  const int b = blockIdx.x;
  const int f32 = *(const int*)(ws + OFF_FLAG);
  const float* hout = (const float*)(ws + OFF_HOUT);
  const int bm = b * S_;

  aw[tid] = ldv(attn_w, tid, f32);
  __syncthreads();
  if (tid < 128) {
    const float* hp = hout + (size_t)(bm + tid) * H_;
    float acc = 0.f;
    for (int k = 0; k < 256; k += 4) {
      float4 h4 = *(const float4*)(hp + k);
      acc += h4.x * aw[k] + h4.y * aw[k + 1] + h4.z * aw[k + 2] + h4.w * aw[k + 3];
    }
    sc[tid] = acc + ldv(attn_b, 0, f32);
  }
  __syncthreads();
  if (tid == 0) {
    int len = lengths[b];
    float mx = -3.4e38f;
    for (int s = 0; s < len; ++s) mx = fmaxf(mx, sc[s]);
    float sum = 0.f;
    for (int s = 0; s < 128; ++s) {
      float v = (s < len) ? __expf(sc[s] - mx) : 0.f;
      sc[s] = v; sum += v;
    }
    float inv = 1.f / sum;
    for (int s = 0; s < 128; ++s) sc[s] *= inv;
  }
  __syncthreads();
  {
    float acc = 0.f;
    for (int s = 0; s < 128; ++s)
      acc += sc[s] * hout[(size_t)(bm + s) * H_ + tid];
    at[tid] = acc;
  }
  __syncthreads();
  for (int cc = 0; cc < 3; ++cc) {
    red[tid] = at[tid] * ldv(out_w, cc * 256 + tid, f32);
    __syncthreads();
    for (int off = 128; off > 0; off >>= 1) {
      if (tid < off) red[tid] += red[tid + off];
      __syncthreads();
    }
    if (tid == 0) {
      float v = red[0] + ldv(out_b, cc, f32);
      if (f32) ((float*)out)[b * 3 + cc] = v;
      else     ((ushort_t*)out)[b * 3 + cc] = f2b(v);
    }
    __syncthreads();
  }
}

// =====================================================================
extern "C" void kernel_launch(void* const* d_in, const int* in_sizes, int n_in,
                              void* d_out, int out_size, void* d_ws, size_t ws_size,
                              hipStream_t stream)
{
  const int* inputs  = (const int*)d_in[0];
  // d_in[1] = context (unused by the reference)
  const int* triples = (const int*)d_in[2];
  const int* lengths = (const int*)d_in[3];
  const int* id2     = (const int*)d_in[4];
  const void* emb    = d_in[5];
  const void* ent    = d_in[6];
  const void* rel    = d_in[7];
  const void* W_ent  = d_in[8];
  const void* W_ih   = d_in[9];
  const void* W_hh   = d_in[10];
  const void* b_lstm = d_in[11];
  const void* attn_w = d_in[12];
  const void* attn_b = d_in[13];
  const void* out_w  = d_in[14];
  const void* out_b  = d_in[15];
  char* ws = (char*)d_ws;

  k_detect<<<dim3(1), dim3(64), 0, stream>>>((const uint_t*)emb, ws);
  k0_prep<<<dim3(2639), dim3(256), 0, stream>>>(W_ent, W_ih, W_hh, ws);
  k1_graph<<<dim3(M_), dim3(128), 0, stream>>>(inputs, triples, id2, emb, ent, rel, ws);
  k2_xg<<<dim3(64, 8), dim3(256), 0, stream>>>(b_lstm, ws);
  k3_lstm<<<dim3(B_), dim3(512), 0, stream>>>(ws);
  k4_attn<<<dim3(B_), dim3(256), 0, stream>>>(lengths, attn_w, attn_b, out_w, out_b, ws, d_out);
}

// Round 3
// 677.078 us; speedup vs baseline: 1.4015x; 1.4015x over previous
//
#include <hip/hip_runtime.h>
#include <cstdint>
#include <cstddef>

typedef unsigned int  uint_t;
typedef unsigned short ushort_t;

// ---- shapes (fixed for this problem) ----
constexpr int B_  = 64;
constexpr int S_  = 128;
constexpr int D_  = 100;   // triple embedding dim
constexpr int E_  = 300;   // word embedding dim
constexpr int H_  = 256;   // hidden
constexpr int KIN = 512;   // LSTM input 500 padded to 512 for MFMA K
constexpr int NG  = 1024;  // 4*H gates
constexpr int M_  = B_ * S_;  // 8192

// K3 weight split: per gate row, 64 f16x2 words; R_ in VGPRs, L_ in LDS
constexpr int L_ = 12;
constexpr int R_ = 64 - L_;   // 52

// ---- workspace layout (bytes) ----
constexpr size_t OFF_WT   = 0;                                  // W_ent^T bf16 [200][100]  (40000 B)
constexpr size_t OFF_FLAG = 40000;                              // int: 1 if inputs are fp32, 0 if bf16
constexpr size_t OFF_WIH  = 40960;                              // W_ih padded bf16 [1024][512]
constexpr size_t OFF_WHH  = OFF_WIH + (size_t)NG * KIN * 2;     // W_hh as f16x2, [128][1024] u32
constexpr size_t OFF_TIN  = OFF_WHH + (size_t)128 * NG * 4;     // t_in bf16 [8192][512]
constexpr size_t OFF_XG   = OFF_TIN + (size_t)M_ * KIN * 2;     // xg f32 [8192][1024]
constexpr size_t OFF_HOUT = OFF_XG + (size_t)M_ * NG * 4;       // h f32 [8192][256]
// total ~50 MB

// ---- helpers ----
__device__ __forceinline__ float b2f(ushort_t u) {
  union { uint_t u; float f; } v; v.u = ((uint_t)u) << 16; return v.f;
}
__device__ __forceinline__ float blo(uint_t u) {
  union { uint_t u; float f; } v; v.u = u << 16; return v.f;
}
__device__ __forceinline__ float bhi(uint_t u) {
  union { uint_t u; float f; } v; v.u = u & 0xffff0000u; return v.f;
}
__device__ __forceinline__ ushort_t f2b(float f) {  // RNE float->bf16
  union { float f; uint_t u; } v; v.f = f;
  uint_t r = (v.u + 0x7fffu + ((v.u >> 16) & 1u)) >> 16;
  return (ushort_t)r;
}
__device__ __forceinline__ ushort_t f16bits(float f) {
  _Float16 h = (_Float16)f;
  union { _Float16 h; ushort_t u; } v; v.h = h; return v.u;
}
__device__ __forceinline__ float fast_tanh(float x) {
  float e = __expf(2.f * x);
  return 1.f - 2.f / (e + 1.f);
}
__device__ __forceinline__ float sigm(float x) {
  return 1.f / (1.f + __expf(-x));
}
// dtype-flexible load of an external "float" tensor
__device__ __forceinline__ float ldv(const void* p, size_t i, int f32) {
  return f32 ? ((const float*)p)[i] : b2f(((const ushort_t*)p)[i]);
}

#if defined(__has_builtin)
#if __has_builtin(__builtin_amdgcn_fdot2)
#define HAVE_FDOT2 1
#endif
#endif

typedef _Float16 half2v __attribute__((ext_vector_type(2)));

__device__ __forceinline__ float dot2(uint_t w, uint_t h, float acc) {
#ifdef HAVE_FDOT2
  union { uint_t u; half2v v; } a, b; a.u = w; b.u = h;
  return __builtin_amdgcn_fdot2(a.v, b.v, acc, false);
#else
  union { uint_t u; _Float16 h[2]; } a, b; a.u = w; b.u = h;
  acc += (float)a.h[0] * (float)b.h[0];
  acc += (float)a.h[1] * (float)b.h[1];
  return acc;
#endif
}

// =====================================================================
// K_detect: decide whether external float tensors are fp32 or bf16.
// =====================================================================
__global__ __launch_bounds__(64) void k_detect(const uint_t* __restrict__ emb_w,
                                               char* __restrict__ ws)
{
  int tid = threadIdx.x;
  int hits = 0;
  for (int i = 0; i < 8; ++i) {
    uint_t w = emb_w[i * 64 + tid];
    uint_t e = (w >> 7) & 0xffu;   // exponent field of lo-ushort-as-bf16
    hits += (e >= 140) ? 1 : 0;
  }
  for (int off = 32; off > 0; off >>= 1) hits += __shfl_down(hits, off);
  if (tid == 0) *(int*)(ws + OFF_FLAG) = (hits >= 32) ? 1 : 0;
}

// =====================================================================
// K0: weight prep. Wt = W_ent^T (bf16); W_ih padded K 500->512 (bf16);
// W_hh -> f16x2 packed, transposed to [kpair][row].
// =====================================================================
__global__ __launch_bounds__(256) void k0_prep(
    const void* __restrict__ W_ent, const void* __restrict__ W_ih,
    const void* __restrict__ W_hh, char* __restrict__ ws)
{
  const int f32 = *(const int*)(ws + OFF_FLAG);
  int id = blockIdx.x * 256 + threadIdx.x;
  ushort_t* Wt = (ushort_t*)(ws + OFF_WT);
  ushort_t* Wp = (ushort_t*)(ws + OFF_WIH);
  uint_t*   WT = (uint_t*)(ws + OFF_WHH);
  if (id < 20000) {
    int k = id / 100, d = id % 100;
    Wt[id] = f2b(ldv(W_ent, (size_t)d * 200 + k, f32));   // Wt[k][d] = W_ent[d][k]
  } else if (id < 20000 + NG * KIN) {
    int i = id - 20000;
    int n = i >> 9, k = i & 511;
    Wp[i] = (k < 500) ? f2b(ldv(W_ih, (size_t)n * 500 + k, f32)) : (ushort_t)0;
  } else if (id < 20000 + NG * KIN + 128 * NG) {
    int i = id - 20000 - NG * KIN;
    int kk = i >> 10, j = i & 1023;
    ushort_t lo = f16bits(ldv(W_hh, (size_t)j * 256 + 2 * kk,     f32));
    ushort_t hi = f16bits(ldv(W_hh, (size_t)j * 256 + 2 * kk + 1, f32));
    WT[kk * 1024 + j] = (uint_t)lo | ((uint_t)hi << 16);
  }
}

// =====================================================================
// K1: triple graph attention per (b,s); writes t_in bf16 [m][512].
// =====================================================================
__global__ __launch_bounds__(128) void k1_graph(
    const int* __restrict__ inputs, const int* __restrict__ triples,
    const int* __restrict__ id2, const void* __restrict__ emb,
    const void* __restrict__ ent, const void* __restrict__ rel,
    char* __restrict__ ws)
{
  __shared__ __align__(16) ushort_t Wl[20000];   // W^T [k][d], 40000 B
  __shared__ float ht_l[10][200];
  __shared__ float er_l[10][100];
  __shared__ float e_l[10];
  __shared__ float alpha_l[10];
  __shared__ int   trip_l[30];
  __shared__ int   vflag;

  const int tid = threadIdx.x;
  const int m   = blockIdx.x;  // b*128+s
  const int f32 = *(const int*)(ws + OFF_FLAG);
  const ushort_t* Wt = (const ushort_t*)(ws + OFF_WT);
  ushort_t* tin = (ushort_t*)(ws + OFF_TIN);

  if (tid < 30) trip_l[tid] = triples[(size_t)m * 30 + tid];
  if (tid == 0) vflag = 0;
  if (tid < 10) e_l[tid] = 0.f;
  __syncthreads();
  if (tid < 10 && id2[(size_t)m * 10 + tid] != -1) atomicOr(&vflag, 1);

  {
    const uint4* src = (const uint4*)Wt;
    uint4* dst = (uint4*)Wl;
    for (int i = tid; i < 2500; i += 128) dst[i] = src[i];
  }
  for (int i = tid; i < 2000; i += 128) {
    int t = i / 200, k = i % 200;
    int row = trip_l[t * 3 + (k < 100 ? 0 : 1)];
    int kk = (k < 100) ? k : k - 100;
    ht_l[t][k] = ldv(ent, (size_t)row * 100 + kk, f32);
  }
  for (int i = tid; i < 1000; i += 128) {
    int t = i / 100, d = i % 100;
    er_l[t][d] = ldv(rel, (size_t)trip_l[t * 3 + 2] * 100 + d, f32);
  }
  {
    int w = inputs[m];
    for (int c = tid; c < 300; c += 128)
      tin[(size_t)m * KIN + c] = f2b(ldv(emb, (size_t)w * E_ + c, f32));
    if (tid < 12) tin[(size_t)m * KIN + 500 + tid] = 0;
  }
  __syncthreads();

  if (tid < 125) {
    int t2 = tid / 25, d4 = tid % 25;
    int t0 = 2 * t2, t1 = t0 + 1;
    float a00 = 0, a01 = 0, a02 = 0, a03 = 0;
    float a10 = 0, a11 = 0, a12 = 0, a13 = 0;
    for (int k = 0; k < 200; ++k) {
      uint2 wu = *(const uint2*)&Wl[k * 100 + 4 * d4];
      float h0 = ht_l[t0][k], h1 = ht_l[t1][k];
      float w0 = blo(wu.x), w1 = bhi(wu.x), w2 = blo(wu.y), w3 = bhi(wu.y);
      a00 += w0 * h0; a01 += w1 * h0; a02 += w2 * h0; a03 += w3 * h0;
      a10 += w0 * h1; a11 += w1 * h1; a12 += w2 * h1; a13 += w3 * h1;
    }
    int d = 4 * d4;
    float s0 = fast_tanh(a00) * er_l[t0][d]     + fast_tanh(a01) * er_l[t0][d + 1]
             + fast_tanh(a02) * er_l[t0][d + 2] + fast_tanh(a03) * er_l[t0][d + 3];
    float s1 = fast_tanh(a10) * er_l[t1][d]     + fast_tanh(a11) * er_l[t1][d + 1]
             + fast_tanh(a12) * er_l[t1][d + 2] + fast_tanh(a13) * er_l[t1][d + 3];
    atomicAdd(&e_l[t0], s0);
    atomicAdd(&e_l[t1], s1);
  }
  __syncthreads();
  if (tid == 0) {
    float mx = e_l[0];
    for (int t = 1; t < 10; ++t) mx = fmaxf(mx, e_l[t]);
    float s = 0.f;
    for (int t = 0; t < 10; ++t) { float v = __expf(e_l[t] - mx); alpha_l[t] = v; s += v; }
    float inv = 1.f / s;
    for (int t = 0; t < 10; ++t) alpha_l[t] *= inv;
  }
  __syncthreads();
  for (int k2 = tid; k2 < 200; k2 += 128) {
    float g = 0.f;
#pragma unroll
    for (int t = 0; t < 10; ++t) g += alpha_l[t] * ht_l[t][k2];
    if (!vflag) g = 0.f;
    tin[(size_t)m * KIN + 300 + k2] = f2b(g);
  }
}

// =====================================================================
// K2: xg = t_in @ W_ih^T + b.  MFMA 16x16x32 bf16, 128x128 tiles, BK=32.
// =====================================================================
typedef __attribute__((ext_vector_type(8))) short short8;
typedef __attribute__((ext_vector_type(4))) float f32x4;

__global__ __launch_bounds__(256) void k2_xg(
    const void* __restrict__ bl, char* __restrict__ ws)
{
  __shared__ __align__(16) ushort_t As[128 * 32];
  __shared__ __align__(16) ushort_t Bs[128 * 32];
  const ushort_t* A  = (const ushort_t*)(ws + OFF_TIN);
  const ushort_t* Bw = (const ushort_t*)(ws + OFF_WIH);
  float* xg = (float*)(ws + OFF_XG);
  const int f32 = *(const int*)(ws + OFF_FLAG);

  const int tid = threadIdx.x;
  const int m0 = blockIdx.x * 128;
  const int n0 = blockIdx.y * 128;
  const int lane = tid & 63, wv = tid >> 6;
  const int wm = wv & 1, wn = wv >> 1;
  const int g = lane >> 4, r = lane & 15;

  f32x4 acc[4][4] = {};

  for (int ks = 0; ks < 16; ++ks) {
    const int k0 = ks * 32;
    {
      int c0 = tid, c1 = tid + 256;
      uint4 a0 = *(const uint4*)(A  + (size_t)(m0 + (c0 >> 2)) * KIN + k0 + ((c0 & 3) << 3));
      uint4 a1 = *(const uint4*)(A  + (size_t)(m0 + (c1 >> 2)) * KIN + k0 + ((c1 & 3) << 3));
      uint4 b0 = *(const uint4*)(Bw + (size_t)(n0 + (c0 >> 2)) * KIN + k0 + ((c0 & 3) << 3));
      uint4 b1 = *(const uint4*)(Bw + (size_t)(n0 + (c1 >> 2)) * KIN + k0 + ((c1 & 3) << 3));
      ((uint4*)As)[c0] = a0; ((uint4*)As)[c1] = a1;
      ((uint4*)Bs)[c0] = b0; ((uint4*)Bs)[c1] = b1;
    }
    __syncthreads();
    short8 av[4], bv[4];
#pragma unroll
    for (int i = 0; i < 4; ++i)
      av[i] = *(const short8*)&As[(wm * 64 + i * 16 + r) * 32 + g * 8];
#pragma unroll
    for (int j = 0; j < 4; ++j)
      bv[j] = *(const short8*)&Bs[(wn * 64 + j * 16 + r) * 32 + g * 8];
#pragma unroll
    for (int i = 0; i < 4; ++i)
#pragma unroll
      for (int j = 0; j < 4; ++j)
        acc[i][j] = __builtin_amdgcn_mfma_f32_16x16x32_bf16(av[i], bv[j], acc[i][j], 0, 0, 0);
    __syncthreads();
  }
#pragma unroll
  for (int j = 0; j < 4; ++j) {
    int n = n0 + wn * 64 + j * 16 + r;
    float bias = ldv(bl, n, f32);
#pragma unroll
    for (int i = 0; i < 4; ++i) {
      int mrow = m0 + wm * 64 + i * 16 + g * 4;
#pragma unroll
      for (int rr = 0; rr < 4; ++rr)
        xg[(size_t)(mrow + rr) * NG + n] = acc[i][j][rr] + bias;
    }
  }
}

// =====================================================================
// K3: recurrent LSTM, hybrid reg+LDS weights.
// 64 blocks (1/batch) x 512 threads. Thread-pair (lanes 2j,2j+1) owns
// hidden unit u = tid>>1: all 4 gate rows {u, u+256, u+512, u+768}.
// K (256 dims = 128 f16x2 words) split in halves across the pair
// (half = tid&1, words [half*64, half*64+64)). Per row: R_=52 words in
// VGPRs, L_=12 words in LDS ([chunk][thread] uint4 layout, stride 16 B
// -> conflict-free ds_read_b128). h double-buffered in LDS as f16;
// one barrier per step. Halves combined via __shfl_xor(.,1).
// __launch_bounds__(512,2): 2 waves/SIMD -> 256-VGPR cap; weights 208.
// =====================================================================
__global__ __launch_bounds__(512, 2) void k3_lstm(char* __restrict__ ws)
{
  extern __shared__ __align__(16) char smem[];
  uint4*    ldsw = (uint4*)smem;                       // [12][512] uint4 = 96 KB
  ushort_t* hbuf = (ushort_t*)(smem + 12 * 512 * 16);  // [2][256] f16

  const int tid  = threadIdx.x;
  const int b    = blockIdx.x;
  const int u    = tid >> 1;          // hidden unit 0..255
  const int half = tid & 1;           // K-half
  const int kbase = half * 64;        // first f16x2 word index of my K-half

  const uint_t* WT = (const uint_t*)(ws + OFF_WHH);  // [kpair][1024]
  const float* xg = (const float*)(ws + OFF_XG);
  float* hout = (float*)(ws + OFF_HOUT);

  const int row[4] = { u, u + 256, u + 512, u + 768 };

  // ---- load register-resident weights: wreg[i][q] = WT[kbase+q][row_i]
  uint_t wreg[4][R_];
#pragma unroll
  for (int i = 0; i < 4; ++i)
#pragma unroll
    for (int q = 0; q < R_; ++q)
      wreg[i][q] = WT[(size_t)(kbase + q) * 1024 + row[i]];

  // ---- stage LDS-resident weights: chunk c = i*3+p holds words
  // kbase+R_+4p .. +3 of row i, at [c][tid] as uint4
#pragma unroll
  for (int i = 0; i < 4; ++i)
#pragma unroll
    for (int p = 0; p < 3; ++p) {
      uint4 v;
      v.x = WT[(size_t)(kbase + R_ + 4 * p + 0) * 1024 + row[i]];
      v.y = WT[(size_t)(kbase + R_ + 4 * p + 1) * 1024 + row[i]];
      v.z = WT[(size_t)(kbase + R_ + 4 * p + 2) * 1024 + row[i]];
      v.w = WT[(size_t)(kbase + R_ + 4 * p + 3) * 1024 + row[i]];
      ldsw[(i * 3 + p) * 512 + tid] = v;
    }
  hbuf[tid] = 0;   // zero both h buffers (512 entries)
  float c = 0.f;
  __syncthreads();

  const int bm = b * S_;
  for (int t = 0; t < S_; ++t) {
    const int cur = t & 1;
    // prefetch xg for my unit's 4 gates (both lanes load same -> L1 hit)
    const float* xp = xg + (size_t)(bm + t) * NG;
    float x0 = xp[row[0]], x1 = xp[row[1]], x2 = xp[row[2]], x3 = xp[row[3]];

    const uint_t* hb = (const uint_t*)(hbuf + cur * 256);  // 128 u32 words
    float a0 = 0.f, a1 = 0.f, a2 = 0.f, a3 = 0.f;
    // register part: 13 uint4 h-reads x 16 dot2
#pragma unroll
    for (int qq = 0; qq < R_ / 4; ++qq) {
      uint4 hv = *(const uint4*)&hb[kbase + 4 * qq];
      a0 = dot2(wreg[0][4 * qq], hv.x, a0); a0 = dot2(wreg[0][4 * qq + 1], hv.y, a0);
      a0 = dot2(wreg[0][4 * qq + 2], hv.z, a0); a0 = dot2(wreg[0][4 * qq + 3], hv.w, a0);
      a1 = dot2(wreg[1][4 * qq], hv.x, a1); a1 = dot2(wreg[1][4 * qq + 1], hv.y, a1);
      a1 = dot2(wreg[1][4 * qq + 2], hv.z, a1); a1 = dot2(wreg[1][4 * qq + 3], hv.w, a1);
      a2 = dot2(wreg[2][4 * qq], hv.x, a2); a2 = dot2(wreg[2][4 * qq + 1], hv.y, a2);
      a2 = dot2(wreg[2][4 * qq + 2], hv.z, a2); a2 = dot2(wreg[2][4 * qq + 3], hv.w, a2);
      a3 = dot2(wreg[3][4 * qq], hv.x, a3); a3 = dot2(wreg[3][4 * qq + 1], hv.y, a3);
      a3 = dot2(wreg[3][4 * qq + 2], hv.z, a3); a3 = dot2(wreg[3][4 * qq + 3], hv.w, a3);
    }
    // LDS part: words kbase+R_ .. kbase+63
#pragma unroll
    for (int p = 0; p < 3; ++p) {
      uint4 hv = *(const uint4*)&hb[kbase + R_ + 4 * p];
      uint4 w0 = ldsw[(0 * 3 + p) * 512 + tid];
      uint4 w1 = ldsw[(1 * 3 + p) * 512 + tid];
      uint4 w2 = ldsw[(2 * 3 + p) * 512 + tid];
      uint4 w3 = ldsw[(3 * 3 + p) * 512 + tid];
      a0 = dot2(w0.x, hv.x, a0); a0 = dot2(w0.y, hv.y, a0);
      a0 = dot2(w0.z, hv.z, a0); a0 = dot2(w0.w, hv.w, a0);
      a1 = dot2(w1.x, hv.x, a1); a1 = dot2(w1.y, hv.y, a1);
      a1 = dot2(w1.z, hv.z, a1); a1 = dot2(w1.w, hv.w, a1);
      a2 = dot2(w2.x, hv.x, a2); a2 = dot2(w2.y, hv.y, a2);
      a2 = dot2(w2.z, hv.z, a2); a2 = dot2(w2.w, hv.w, a2);
      a3 = dot2(w3.x, hv.x, a3); a3 = dot2(w3.y, hv.y, a3);
      a3 = dot2(w3.z, hv.z, a3); a3 = dot2(w3.w, hv.w, a3);
    }
    // combine K-halves (both lanes get full sums)
    float gi = a0 + __shfl_xor(a0, 1) + x0;
    float gf = a1 + __shfl_xor(a1, 1) + x1;
    float gg = a2 + __shfl_xor(a2, 1) + x2;
    float go = a3 + __shfl_xor(a3, 1) + x3;
    c = sigm(gf) * c + sigm(gi) * fast_tanh(gg);
    float hv = sigm(go) * fast_tanh(c);
    if (!half) {
      hout[(size_t)(bm + t) * H_ + u] = hv;
      hbuf[(cur ^ 1) * 256 + u] = f16bits(hv);
    }
    __syncthreads();
  }
}

// =====================================================================
// K4: masked attention pooling + logits. One block per batch.
// =====================================================================
__global__ __launch_bounds__(256) void k4_attn(
    const int* __restrict__ lengths, const void* __restrict__ attn_w,
    const void* __restrict__ attn_b, const void* __restrict__ out_w,
    const void* __restrict__ out_b, const char* __restrict__ ws,
    void* __restrict__ out)
{
  __shared__ float aw[256];
  __shared__ float sc[128];
  __shared__ float at[256];
  __shared__ float red[256];

  const int tid = threadIdx.x;
  const int b = blockIdx.x;
  const int f32 = *(const int*)(ws + OFF_FLAG);
  const float* hout = (const float*)(ws + OFF_HOUT);
  const int bm = b * S_;

  aw[tid] = ldv(attn_w, tid, f32);
  __syncthreads();
  if (tid < 128) {
    const float* hp = hout + (size_t)(bm + tid) * H_;
    float acc = 0.f;
    for (int k = 0; k < 256; k += 4) {
      float4 h4 = *(const float4*)(hp + k);
      acc += h4.x * aw[k] + h4.y * aw[k + 1] + h4.z * aw[k + 2] + h4.w * aw[k + 3];
    }
    sc[tid] = acc + ldv(attn_b, 0, f32);
  }
  __syncthreads();
  if (tid == 0) {
    int len = lengths[b];
    float mx = -3.4e38f;
    for (int s = 0; s < len; ++s) mx = fmaxf(mx, sc[s]);
    float sum = 0.f;
    for (int s = 0; s < 128; ++s) {
      float v = (s < len) ? __expf(sc[s] - mx) : 0.f;
      sc[s] = v; sum += v;
    }
    float inv = 1.f / sum;
    for (int s = 0; s < 128; ++s) sc[s] *= inv;
  }
  __syncthreads();
  {
    float acc = 0.f;
    for (int s = 0; s < 128; ++s)
      acc += sc[s] * hout[(size_t)(bm + s) * H_ + tid];
    at[tid] = acc;
  }
  __syncthreads();
  for (int cc = 0; cc < 3; ++cc) {
    red[tid] = at[tid] * ldv(out_w, cc * 256 + tid, f32);
    __syncthreads();
    for (int off = 128; off > 0; off >>= 1) {
      if (tid < off) red[tid] += red[tid + off];
      __syncthreads();
    }
    if (tid == 0) {
      float v = red[0] + ldv(out_b, cc, f32);
      if (f32) ((float*)out)[b * 3 + cc] = v;
      else     ((ushort_t*)out)[b * 3 + cc] = f2b(v);
    }
    __syncthreads();
  }
}

// =====================================================================
extern "C" void kernel_launch(void* const* d_in, const int* in_sizes, int n_in,
                              void* d_out, int out_size, void* d_ws, size_t ws_size,
                              hipStream_t stream)
{
  const int* inputs  = (const int*)d_in[0];
  const int* triples = (const int*)d_in[2];
  const int* lengths = (const int*)d_in[3];
  const int* id2     = (const int*)d_in[4];
  const void* emb    = d_in[5];
  const void* ent    = d_in[6];
  const void* rel    = d_in[7];
  const void* W_ent  = d_in[8];
  const void* W_ih   = d_in[9];
  const void* W_hh   = d_in[10];
  const void* b_lstm = d_in[11];
  const void* attn_w = d_in[12];
  const void* attn_b = d_in[13];
  const void* out_w  = d_in[14];
  const void* out_b  = d_in[15];
  char* ws = (char*)d_ws;

  constexpr int K3_SMEM = 12 * 512 * 16 + 2 * 256 * 2;  // 99328 B
  static bool attr_set = false;
  if (!attr_set) {
    (void)hipFuncSetAttribute((const void*)k3_lstm,
                              hipFuncAttributeMaxDynamicSharedMemorySize, K3_SMEM);
    attr_set = true;
  }

  k_detect<<<dim3(1), dim3(64), 0, stream>>>((const uint_t*)emb, ws);
  k0_prep<<<dim3(2639), dim3(256), 0, stream>>>(W_ent, W_ih, W_hh, ws);
  k1_graph<<<dim3(M_), dim3(128), 0, stream>>>(inputs, triples, id2, emb, ent, rel, ws);
  k2_xg<<<dim3(64, 8), dim3(256), 0, stream>>>(b_lstm, ws);
  k3_lstm<<<dim3(B_), dim3(512), K3_SMEM, stream>>>(ws);
  k4_attn<<<dim3(B_), dim3(256), 0, stream>>>(lengths, attn_w, attn_b, out_w, out_b, ws, d_out);
}

// Round 4
// 640.228 us; speedup vs baseline: 1.4822x; 1.0576x over previous
//
#include <hip/hip_runtime.h>
#include <cstdint>
#include <cstddef>

typedef unsigned int  uint_t;
typedef unsigned short ushort_t;

// ---- shapes (fixed for this problem) ----
constexpr int B_  = 64;
constexpr int S_  = 128;
constexpr int D_  = 100;   // triple embedding dim
constexpr int E_  = 300;   // word embedding dim
constexpr int H_  = 256;   // hidden
constexpr int KIN = 512;   // LSTM input 500 padded to 512 for MFMA K
constexpr int NG  = 1024;  // 4*H gates
constexpr int M_  = B_ * S_;  // 8192

// K3 weight split: per gate row, each thread owns 64 f16x2 words (half of K);
// RW in VGPRs, LW in LDS.
constexpr int RW = 48;
constexpr int LW = 16;   // 4 chunks of 4 words

// ---- workspace layout (bytes) ----
constexpr size_t OFF_WT   = 0;                                  // W_ent^T bf16 [200][100]  (40000 B)
constexpr size_t OFF_FLAG = 40000;                              // int: 1 if inputs are fp32, 0 if bf16
constexpr size_t OFF_WIH  = 40960;                              // W_ih padded bf16 [1024][512]
constexpr size_t OFF_WHH  = OFF_WIH + (size_t)NG * KIN * 2;     // W_hh as f16x2, [128][1024] u32
constexpr size_t OFF_TIN  = OFF_WHH + (size_t)128 * NG * 4;     // t_in bf16 [8192][512]
constexpr size_t OFF_XG   = OFF_TIN + (size_t)M_ * KIN * 2;     // xg f32 [8192][1024]
constexpr size_t OFF_HOUT = OFF_XG + (size_t)M_ * NG * 4;       // h f32 [8192][256]
// total ~50 MB

// ---- helpers ----
__device__ __forceinline__ float b2f(ushort_t u) {
  union { uint_t u; float f; } v; v.u = ((uint_t)u) << 16; return v.f;
}
__device__ __forceinline__ float blo(uint_t u) {
  union { uint_t u; float f; } v; v.u = u << 16; return v.f;
}
__device__ __forceinline__ float bhi(uint_t u) {
  union { uint_t u; float f; } v; v.u = u & 0xffff0000u; return v.f;
}
__device__ __forceinline__ ushort_t f2b(float f) {  // RNE float->bf16
  union { float f; uint_t u; } v; v.f = f;
  uint_t r = (v.u + 0x7fffu + ((v.u >> 16) & 1u)) >> 16;
  return (ushort_t)r;
}
__device__ __forceinline__ ushort_t f16bits(float f) {
  _Float16 h = (_Float16)f;
  union { _Float16 h; ushort_t u; } v; v.h = h; return v.u;
}
__device__ __forceinline__ float fast_tanh(float x) {
  float e = __expf(2.f * x);
  return 1.f - 2.f / (e + 1.f);
}
__device__ __forceinline__ float sigm(float x) {
  return 1.f / (1.f + __expf(-x));
}
// dtype-flexible load of an external "float" tensor
__device__ __forceinline__ float ldv(const void* p, size_t i, int f32) {
  return f32 ? ((const float*)p)[i] : b2f(((const ushort_t*)p)[i]);
}

#if defined(__has_builtin)
#if __has_builtin(__builtin_amdgcn_fdot2)
#define HAVE_FDOT2 1
#endif
#endif

typedef _Float16 half2v __attribute__((ext_vector_type(2)));

__device__ __forceinline__ float dot2(uint_t w, uint_t h, float acc) {
#ifdef HAVE_FDOT2
  union { uint_t u; half2v v; } a, b; a.u = w; b.u = h;
  return __builtin_amdgcn_fdot2(a.v, b.v, acc, false);
#else
  union { uint_t u; _Float16 h[2]; } a, b; a.u = w; b.u = h;
  acc += (float)a.h[0] * (float)b.h[0];
  acc += (float)a.h[1] * (float)b.h[1];
  return acc;
#endif
}

// =====================================================================
// K_detect: decide whether external float tensors are fp32 or bf16.
// =====================================================================
__global__ __launch_bounds__(64) void k_detect(const uint_t* __restrict__ emb_w,
                                               char* __restrict__ ws)
{
  int tid = threadIdx.x;
  int hits = 0;
  for (int i = 0; i < 8; ++i) {
    uint_t w = emb_w[i * 64 + tid];
    uint_t e = (w >> 7) & 0xffu;   // exponent field of lo-ushort-as-bf16
    hits += (e >= 140) ? 1 : 0;
  }
  for (int off = 32; off > 0; off >>= 1) hits += __shfl_down(hits, off);
  if (tid == 0) *(int*)(ws + OFF_FLAG) = (hits >= 32) ? 1 : 0;
}

// =====================================================================
// K0: weight prep. Wt = W_ent^T (bf16); W_ih padded K 500->512 (bf16);
// W_hh -> f16x2 packed, transposed to [kpair][row].
// =====================================================================
__global__ __launch_bounds__(256) void k0_prep(
    const void* __restrict__ W_ent, const void* __restrict__ W_ih,
    const void* __restrict__ W_hh, char* __restrict__ ws)
{
  const int f32 = *(const int*)(ws + OFF_FLAG);
  int id = blockIdx.x * 256 + threadIdx.x;
  ushort_t* Wt = (ushort_t*)(ws + OFF_WT);
  ushort_t* Wp = (ushort_t*)(ws + OFF_WIH);
  uint_t*   WT = (uint_t*)(ws + OFF_WHH);
  if (id < 20000) {
    int k = id / 100, d = id % 100;
    Wt[id] = f2b(ldv(W_ent, (size_t)d * 200 + k, f32));   // Wt[k][d] = W_ent[d][k]
  } else if (id < 20000 + NG * KIN) {
    int i = id - 20000;
    int n = i >> 9, k = i & 511;
    Wp[i] = (k < 500) ? f2b(ldv(W_ih, (size_t)n * 500 + k, f32)) : (ushort_t)0;
  } else if (id < 20000 + NG * KIN + 128 * NG) {
    int i = id - 20000 - NG * KIN;
    int kk = i >> 10, j = i & 1023;
    ushort_t lo = f16bits(ldv(W_hh, (size_t)j * 256 + 2 * kk,     f32));
    ushort_t hi = f16bits(ldv(W_hh, (size_t)j * 256 + 2 * kk + 1, f32));
    WT[kk * 1024 + j] = (uint_t)lo | ((uint_t)hi << 16);
  }
}

// =====================================================================
// K1: triple graph attention per (b,s); writes t_in bf16 [m][512].
// =====================================================================
__global__ __launch_bounds__(128) void k1_graph(
    const int* __restrict__ inputs, const int* __restrict__ triples,
    const int* __restrict__ id2, const void* __restrict__ emb,
    const void* __restrict__ ent, const void* __restrict__ rel,
    char* __restrict__ ws)
{
  __shared__ __align__(16) ushort_t Wl[20000];   // W^T [k][d], 40000 B
  __shared__ float ht_l[10][200];
  __shared__ float er_l[10][100];
  __shared__ float e_l[10];
  __shared__ float alpha_l[10];
  __shared__ int   trip_l[30];
  __shared__ int   vflag;

  const int tid = threadIdx.x;
  const int m   = blockIdx.x;  // b*128+s
  const int f32 = *(const int*)(ws + OFF_FLAG);
  const ushort_t* Wt = (const ushort_t*)(ws + OFF_WT);
  ushort_t* tin = (ushort_t*)(ws + OFF_TIN);

  if (tid < 30) trip_l[tid] = triples[(size_t)m * 30 + tid];
  if (tid == 0) vflag = 0;
  if (tid < 10) e_l[tid] = 0.f;
  __syncthreads();
  if (tid < 10 && id2[(size_t)m * 10 + tid] != -1) atomicOr(&vflag, 1);

  {
    const uint4* src = (const uint4*)Wt;
    uint4* dst = (uint4*)Wl;
    for (int i = tid; i < 2500; i += 128) dst[i] = src[i];
  }
  for (int i = tid; i < 2000; i += 128) {
    int t = i / 200, k = i % 200;
    int row = trip_l[t * 3 + (k < 100 ? 0 : 1)];
    int kk = (k < 100) ? k : k - 100;
    ht_l[t][k] = ldv(ent, (size_t)row * 100 + kk, f32);
  }
  for (int i = tid; i < 1000; i += 128) {
    int t = i / 100, d = i % 100;
    er_l[t][d] = ldv(rel, (size_t)trip_l[t * 3 + 2] * 100 + d, f32);
  }
  {
    int w = inputs[m];
    for (int c = tid; c < 300; c += 128)
      tin[(size_t)m * KIN + c] = f2b(ldv(emb, (size_t)w * E_ + c, f32));
    if (tid < 12) tin[(size_t)m * KIN + 500 + tid] = 0;
  }
  __syncthreads();

  if (tid < 125) {
    int t2 = tid / 25, d4 = tid % 25;
    int t0 = 2 * t2, t1 = t0 + 1;
    float a00 = 0, a01 = 0, a02 = 0, a03 = 0;
    float a10 = 0, a11 = 0, a12 = 0, a13 = 0;
    for (int k = 0; k < 200; ++k) {
      uint2 wu = *(const uint2*)&Wl[k * 100 + 4 * d4];
      float h0 = ht_l[t0][k], h1 = ht_l[t1][k];
      float w0 = blo(wu.x), w1 = bhi(wu.x), w2 = blo(wu.y), w3 = bhi(wu.y);
      a00 += w0 * h0; a01 += w1 * h0; a02 += w2 * h0; a03 += w3 * h0;
      a10 += w0 * h1; a11 += w1 * h1; a12 += w2 * h1; a13 += w3 * h1;
    }
    int d = 4 * d4;
    float s0 = fast_tanh(a00) * er_l[t0][d]     + fast_tanh(a01) * er_l[t0][d + 1]
             + fast_tanh(a02) * er_l[t0][d + 2] + fast_tanh(a03) * er_l[t0][d + 3];
    float s1 = fast_tanh(a10) * er_l[t1][d]     + fast_tanh(a11) * er_l[t1][d + 1]
             + fast_tanh(a12) * er_l[t1][d + 2] + fast_tanh(a13) * er_l[t1][d + 3];
    atomicAdd(&e_l[t0], s0);
    atomicAdd(&e_l[t1], s1);
  }
  __syncthreads();
  if (tid == 0) {
    float mx = e_l[0];
    for (int t = 1; t < 10; ++t) mx = fmaxf(mx, e_l[t]);
    float s = 0.f;
    for (int t = 0; t < 10; ++t) { float v = __expf(e_l[t] - mx); alpha_l[t] = v; s += v; }
    float inv = 1.f / s;
    for (int t = 0; t < 10; ++t) alpha_l[t] *= inv;
  }
  __syncthreads();
  for (int k2 = tid; k2 < 200; k2 += 128) {
    float g = 0.f;
#pragma unroll
    for (int t = 0; t < 10; ++t) g += alpha_l[t] * ht_l[t][k2];
    if (!vflag) g = 0.f;
    tin[(size_t)m * KIN + 300 + k2] = f2b(g);
  }
}

// =====================================================================
// K2: xg = t_in @ W_ih^T + b.  MFMA 16x16x32 bf16, 128x128 tiles, BK=32.
// =====================================================================
typedef __attribute__((ext_vector_type(8))) short short8;
typedef __attribute__((ext_vector_type(4))) float f32x4;

__global__ __launch_bounds__(256) void k2_xg(
    const void* __restrict__ bl, char* __restrict__ ws)
{
  __shared__ __align__(16) ushort_t As[128 * 32];
  __shared__ __align__(16) ushort_t Bs[128 * 32];
  const ushort_t* A  = (const ushort_t*)(ws + OFF_TIN);
  const ushort_t* Bw = (const ushort_t*)(ws + OFF_WIH);
  float* xg = (float*)(ws + OFF_XG);
  const int f32 = *(const int*)(ws + OFF_FLAG);

  const int tid = threadIdx.x;
  const int m0 = blockIdx.x * 128;
  const int n0 = blockIdx.y * 128;
  const int lane = tid & 63, wv = tid >> 6;
  const int wm = wv & 1, wn = wv >> 1;
  const int g = lane >> 4, r = lane & 15;

  f32x4 acc[4][4] = {};

  for (int ks = 0; ks < 16; ++ks) {
    const int k0 = ks * 32;
    {
      int c0 = tid, c1 = tid + 256;
      uint4 a0 = *(const uint4*)(A  + (size_t)(m0 + (c0 >> 2)) * KIN + k0 + ((c0 & 3) << 3));
      uint4 a1 = *(const uint4*)(A  + (size_t)(m0 + (c1 >> 2)) * KIN + k0 + ((c1 & 3) << 3));
      uint4 b0 = *(const uint4*)(Bw + (size_t)(n0 + (c0 >> 2)) * KIN + k0 + ((c0 & 3) << 3));
      uint4 b1 = *(const uint4*)(Bw + (size_t)(n0 + (c1 >> 2)) * KIN + k0 + ((c1 & 3) << 3));
      ((uint4*)As)[c0] = a0; ((uint4*)As)[c1] = a1;
      ((uint4*)Bs)[c0] = b0; ((uint4*)Bs)[c1] = b1;
    }
    __syncthreads();
    short8 av[4], bv[4];
#pragma unroll
    for (int i = 0; i < 4; ++i)
      av[i] = *(const short8*)&As[(wm * 64 + i * 16 + r) * 32 + g * 8];
#pragma unroll
    for (int j = 0; j < 4; ++j)
      bv[j] = *(const short8*)&Bs[(wn * 64 + j * 16 + r) * 32 + g * 8];
#pragma unroll
    for (int i = 0; i < 4; ++i)
#pragma unroll
      for (int j = 0; j < 4; ++j)
        acc[i][j] = __builtin_amdgcn_mfma_f32_16x16x32_bf16(av[i], bv[j], acc[i][j], 0, 0, 0);
    __syncthreads();
  }
#pragma unroll
  for (int j = 0; j < 4; ++j) {
    int n = n0 + wn * 64 + j * 16 + r;
    float bias = ldv(bl, n, f32);
#pragma unroll
    for (int i = 0; i < 4; ++i) {
      int mrow = m0 + wm * 64 + i * 16 + g * 4;
#pragma unroll
      for (int rr = 0; rr < 4; ++rr)
        xg[(size_t)(mrow + rr) * NG + n] = acc[i][j][rr] + bias;
    }
  }
}

// =====================================================================
// K3: recurrent LSTM, hybrid reg+LDS weights, occupancy pinned.
// 64 blocks (1/batch) x 512 threads (8 waves = 2/SIMD, pinned via
// amdgpu_waves_per_eu(2,2) -> 256-VGPR budget the allocator can use).
// Thread-pair (lanes 2j,2j+1) owns hidden unit u=tid>>1, all 4 gate
// rows {u,u+256,u+512,u+768}; K split in halves across the pair
// (half=tid&1 -> words [64*half, 64*half+64)). Per row: RW=48 words in
// VGPRs (4x48=192 regs), LW=16 words in LDS ([chunk][tid] uint4,
// conflict-free b128). h double-buffered in LDS as f16x2; one barrier
// per step; xg software-prefetched one step ahead.
// =====================================================================
__global__ __attribute__((amdgpu_waves_per_eu(2, 2))) __launch_bounds__(512)
void k3_lstm(char* __restrict__ ws)
{
  extern __shared__ __align__(16) char smem[];
  uint4*    ldsw = (uint4*)smem;                          // [16][512] uint4 = 128 KB
  ushort_t* hbuf = (ushort_t*)(smem + 16 * 512 * 16);     // [2][256] f16

  const int tid  = threadIdx.x;
  const int b    = blockIdx.x;
  const int u    = tid >> 1;          // hidden unit 0..255
  const int half = tid & 1;           // K-half
  const int kbase = half * 64;        // first f16x2 word of my K-half

  const uint_t* WT = (const uint_t*)(ws + OFF_WHH);  // [kpair][1024]
  const float* xg = (const float*)(ws + OFF_XG);
  float* hout = (float*)(ws + OFF_HOUT);

  const int row0 = u, row1 = u + 256, row2 = u + 512, row3 = u + 768;

  // ---- register-resident weights: 4 rows x RW words
  uint_t w0[RW], w1[RW], w2[RW], w3[RW];
#pragma unroll
  for (int q = 0; q < RW; ++q) {
    w0[q] = WT[(size_t)(kbase + q) * 1024 + row0];
    w1[q] = WT[(size_t)(kbase + q) * 1024 + row1];
    w2[q] = WT[(size_t)(kbase + q) * 1024 + row2];
    w3[q] = WT[(size_t)(kbase + q) * 1024 + row3];
  }
  // ---- LDS-resident weights: chunk c=i*4+p holds words kbase+RW+4p..+3 of row i
  {
    const int rows[4] = { row0, row1, row2, row3 };
#pragma unroll
    for (int i = 0; i < 4; ++i)
#pragma unroll
      for (int p = 0; p < 4; ++p) {
        uint4 v;
        v.x = WT[(size_t)(kbase + RW + 4 * p + 0) * 1024 + rows[i]];
        v.y = WT[(size_t)(kbase + RW + 4 * p + 1) * 1024 + rows[i]];
        v.z = WT[(size_t)(kbase + RW + 4 * p + 2) * 1024 + rows[i]];
        v.w = WT[(size_t)(kbase + RW + 4 * p + 3) * 1024 + rows[i]];
        ldsw[(i * 4 + p) * 512 + tid] = v;
      }
  }
  hbuf[tid] = 0;   // zero both h buffers (512 f16 entries)
  float c = 0.f;
  __syncthreads();

  const int bm = b * S_;
  // prefetch xg for t=0
  const float* xp0 = xg + (size_t)bm * NG;
  float xn0 = xp0[row0], xn1 = xp0[row1], xn2 = xp0[row2], xn3 = xp0[row3];

  for (int t = 0; t < S_; ++t) {
    const int cur = t & 1;
    float x0 = xn0, x1 = xn1, x2 = xn2, x3 = xn3;
    if (t + 1 < S_) {   // prefetch next step's gate inputs
      const float* xq = xg + (size_t)(bm + t + 1) * NG;
      xn0 = xq[row0]; xn1 = xq[row1]; xn2 = xq[row2]; xn3 = xq[row3];
    }
    const uint_t* hb = (const uint_t*)(hbuf + cur * 256);
    float a0 = 0.f, a1 = 0.f, a2 = 0.f, a3 = 0.f;
    // register part: 12 uint4 h-reads x 16 dot2
#pragma unroll
    for (int qq = 0; qq < RW / 4; ++qq) {
      uint4 hv = *(const uint4*)&hb[kbase + 4 * qq];
      a0 = dot2(w0[4 * qq], hv.x, a0); a0 = dot2(w0[4 * qq + 1], hv.y, a0);
      a0 = dot2(w0[4 * qq + 2], hv.z, a0); a0 = dot2(w0[4 * qq + 3], hv.w, a0);
      a1 = dot2(w1[4 * qq], hv.x, a1); a1 = dot2(w1[4 * qq + 1], hv.y, a1);
      a1 = dot2(w1[4 * qq + 2], hv.z, a1); a1 = dot2(w1[4 * qq + 3], hv.w, a1);
      a2 = dot2(w2[4 * qq], hv.x, a2); a2 = dot2(w2[4 * qq + 1], hv.y, a2);
      a2 = dot2(w2[4 * qq + 2], hv.z, a2); a2 = dot2(w2[4 * qq + 3], hv.w, a2);
      a3 = dot2(w3[4 * qq], hv.x, a3); a3 = dot2(w3[4 * qq + 1], hv.y, a3);
      a3 = dot2(w3[4 * qq + 2], hv.z, a3); a3 = dot2(w3[4 * qq + 3], hv.w, a3);
    }
    // LDS part: words kbase+RW .. kbase+63
#pragma unroll
    for (int p = 0; p < 4; ++p) {
      uint4 hv = *(const uint4*)&hb[kbase + RW + 4 * p];
      uint4 v0 = ldsw[(0 * 4 + p) * 512 + tid];
      uint4 v1 = ldsw[(1 * 4 + p) * 512 + tid];
      uint4 v2 = ldsw[(2 * 4 + p) * 512 + tid];
      uint4 v3 = ldsw[(3 * 4 + p) * 512 + tid];
      a0 = dot2(v0.x, hv.x, a0); a0 = dot2(v0.y, hv.y, a0);
      a0 = dot2(v0.z, hv.z, a0); a0 = dot2(v0.w, hv.w, a0);
      a1 = dot2(v1.x, hv.x, a1); a1 = dot2(v1.y, hv.y, a1);
      a1 = dot2(v1.z, hv.z, a1); a1 = dot2(v1.w, hv.w, a1);
      a2 = dot2(v2.x, hv.x, a2); a2 = dot2(v2.y, hv.y, a2);
      a2 = dot2(v2.z, hv.z, a2); a2 = dot2(v2.w, hv.w, a2);
      a3 = dot2(v3.x, hv.x, a3); a3 = dot2(v3.y, hv.y, a3);
      a3 = dot2(v3.z, hv.z, a3); a3 = dot2(v3.w, hv.w, a3);
    }
    // combine K-halves (both lanes end with identical full sums)
    float gi = a0 + __shfl_xor(a0, 1) + x0;
    float gf = a1 + __shfl_xor(a1, 1) + x1;
    float gg = a2 + __shfl_xor(a2, 1) + x2;
    float go = a3 + __shfl_xor(a3, 1) + x3;
    c = sigm(gf) * c + sigm(gi) * fast_tanh(gg);
    float hv = sigm(go) * fast_tanh(c);
    if (!half) {
      hout[(size_t)(bm + t) * H_ + u] = hv;
      hbuf[(cur ^ 1) * 256 + u] = f16bits(hv);
    }
    __syncthreads();
  }
}

// =====================================================================
// K4: masked attention pooling + logits. One block per batch.
// =====================================================================
__global__ __launch_bounds__(256) void k4_attn(
    const int* __restrict__ lengths, const void* __restrict__ attn_w,
    const void* __restrict__ attn_b, const void* __restrict__ out_w,
    const void* __restrict__ out_b, const char* __restrict__ ws,
    void* __restrict__ out)
{
  __shared__ float aw[256];
  __shared__ float sc[128];
  __shared__ float at[256];
  __shared__ float red[256];

  const int tid = threadIdx.x;
  const int b = blockIdx.x;
  const int f32 = *(const int*)(ws + OFF_FLAG);
  const float* hout = (const float*)(ws + OFF_HOUT);
  const int bm = b * S_;

  aw[tid] = ldv(attn_w, tid, f32);
  __syncthreads();
  if (tid < 128) {
    const float* hp = hout + (size_t)(bm + tid) * H_;
    float acc = 0.f;
    for (int k = 0; k < 256; k += 4) {
      float4 h4 = *(const float4*)(hp + k);
      acc += h4.x * aw[k] + h4.y * aw[k + 1] + h4.z * aw[k + 2] + h4.w * aw[k + 3];
    }
    sc[tid] = acc + ldv(attn_b, 0, f32);
  }
  __syncthreads();
  if (tid == 0) {
    int len = lengths[b];
    float mx = -3.4e38f;
    for (int s = 0; s < len; ++s) mx = fmaxf(mx, sc[s]);
    float sum = 0.f;
    for (int s = 0; s < 128; ++s) {
      float v = (s < len) ? __expf(sc[s] - mx) : 0.f;
      sc[s] = v; sum += v;
    }
    float inv = 1.f / sum;
    for (int s = 0; s < 128; ++s) sc[s] *= inv;
  }
  __syncthreads();
  {
    float acc = 0.f;
    for (int s = 0; s < 128; ++s)
      acc += sc[s] * hout[(size_t)(bm + s) * H_ + tid];
    at[tid] = acc;
  }
  __syncthreads();
  for (int cc = 0; cc < 3; ++cc) {
    red[tid] = at[tid] * ldv(out_w, cc * 256 + tid, f32);
    __syncthreads();
    for (int off = 128; off > 0; off >>= 1) {
      if (tid < off) red[tid] += red[tid + off];
      __syncthreads();
    }
    if (tid == 0) {
      float v = red[0] + ldv(out_b, cc, f32);
      if (f32) ((float*)out)[b * 3 + cc] = v;
      else     ((ushort_t*)out)[b * 3 + cc] = f2b(v);
    }
    __syncthreads();
  }
}

// =====================================================================
extern "C" void kernel_launch(void* const* d_in, const int* in_sizes, int n_in,
                              void* d_out, int out_size, void* d_ws, size_t ws_size,
                              hipStream_t stream)
{
  const int* inputs  = (const int*)d_in[0];
  const int* triples = (const int*)d_in[2];
  const int* lengths = (const int*)d_in[3];
  const int* id2     = (const int*)d_in[4];
  const void* emb    = d_in[5];
  const void* ent    = d_in[6];
  const void* rel    = d_in[7];
  const void* W_ent  = d_in[8];
  const void* W_ih   = d_in[9];
  const void* W_hh   = d_in[10];
  const void* b_lstm = d_in[11];
  const void* attn_w = d_in[12];
  const void* attn_b = d_in[13];
  const void* out_w  = d_in[14];
  const void* out_b  = d_in[15];
  char* ws = (char*)d_ws;

  constexpr int K3_SMEM = 16 * 512 * 16 + 2 * 256 * 2;  // 132096 B
  static bool attr_set = false;
  if (!attr_set) {
    (void)hipFuncSetAttribute((const void*)k3_lstm,
                              hipFuncAttributeMaxDynamicSharedMemorySize, K3_SMEM);
    attr_set = true;
  }

  k_detect<<<dim3(1), dim3(64), 0, stream>>>((const uint_t*)emb, ws);
  k0_prep<<<dim3(2639), dim3(256), 0, stream>>>(W_ent, W_ih, W_hh, ws);
  k1_graph<<<dim3(M_), dim3(128), 0, stream>>>(inputs, triples, id2, emb, ent, rel, ws);
  k2_xg<<<dim3(64, 8), dim3(256), 0, stream>>>(b_lstm, ws);
  k3_lstm<<<dim3(B_), dim3(512), K3_SMEM, stream>>>(ws);
  k4_attn<<<dim3(B_), dim3(256), 0, stream>>>(lengths, attn_w, attn_b, out_w, out_b, ws, d_out);
}